// Round 9
// baseline (43.964 us; speedup 1.0000x reference)
//
#include <hip/hip_runtime.h>

#define BLOCK 256
#define PPT   2                 // points per thread (hand-unrolled, NO arrays)

typedef _Float16 half2v __attribute__((ext_vector_type(2)));
typedef _Float16 half4v __attribute__((ext_vector_type(4)));
typedef float    float4v __attribute__((ext_vector_type(4)));

__device__ __forceinline__ half2v cvt_pk_h2(float a, float b) {
    return __builtin_bit_cast(half2v, __builtin_amdgcn_cvt_pkrtz(a, b));
}

// build half4 from two packed-fp16 dwords (w0 -> elems 0,1; w1 -> elems 2,3)
__device__ __forceinline__ half4v mk_h4(unsigned w0, unsigned w1) {
    uint2 u; u.x = w0; u.y = w1;
    return __builtin_bit_cast(half4v, u);
}

// (hi<<16)|(lo>>16)
__device__ __forceinline__ unsigned align16(unsigned hi_, unsigned lo_) {
    return (hi_ << 16) | (lo_ >> 16);
}

#define H4(x) {(_Float16)(x), (_Float16)(x), (_Float16)(x), (_Float16)(x)}

// Packed-fp16 tanh: odd poly t*p(t^2), deg-5 in s, fit on s in [0,9], clamp
// |x|<=3, endpoint lifted so saturated units land on exactly +-1.0.
__device__ __forceinline__ half4v tanh_pk4(half4v x) {
    const half4v c5 = H4(-3.71625e-05f);
    const half4v c4 = H4( 1.09648e-03f);
    const half4v c3 = H4(-1.288264e-02f);
    const half4v c2 = H4( 7.941906e-02f);
    const half4v c1 = H4(-3.0042735e-01f);
    const half4v c0 = H4( 9.9607644e-01f);
    const half4v hi = H4( 3.0f);
    const half4v lo = H4(-3.0f);
    half4v t = __builtin_elementwise_min(__builtin_elementwise_max(x, lo), hi);
    half4v s = t * t;
#if __has_builtin(__builtin_elementwise_fma)
    half4v p = __builtin_elementwise_fma(c5, s, c4);
    p = __builtin_elementwise_fma(p, s, c3);
    p = __builtin_elementwise_fma(p, s, c2);
    p = __builtin_elementwise_fma(p, s, c1);
    p = __builtin_elementwise_fma(p, s, c0);
#else
    half4v p = c5 * s + c4;
    p = p * s + c3;
    p = p * s + c2;
    p = p * s + c1;
    p = p * s + c0;
#endif
    return t * p;
}

__device__ __forceinline__ half4v pk4_from_f32(float a, float b, float c, float d) {
    half2v lo = cvt_pk_h2(a, b);
    half2v hi = cvt_pk_h2(c, d);
    return __builtin_shufflevector(lo, hi, 0, 1, 2, 3);
}

__device__ __forceinline__ half4v act4(float4v d) {
    return tanh_pk4(pk4_from_f32(d[0], d[1], d[2], d[3]));
}

// Fused prep: (a) pack forcings into float4 table F, (b) block 0 lanes 0..63
// build the per-lane MFMA weight-fragment table (128 B/lane) so the main
// kernel never rebuilds fragments (was ~30 divergent loads + cvts per wave).
__global__ __launch_bounds__(BLOCK) void prep_kernel(
    const float* __restrict__ precp_s, const float* __restrict__ temp_s,
    const float* __restrict__ lday_s,
    const float* __restrict__ etW1, const float* __restrict__ etb1,
    const float* __restrict__ etW2, const float* __restrict__ etb2,
    const float* __restrict__ etW3, const float* __restrict__ etb3,
    const float* __restrict__ qW1, const float* __restrict__ qb1,
    const float* __restrict__ qW2, const float* __restrict__ qb2,
    const float* __restrict__ qW3, const float* __restrict__ qb3,
    float4* __restrict__ F, char* __restrict__ tbl, int T)
{
    int i = blockIdx.x * BLOCK + threadIdx.x;
    if (i < T) F[i] = make_float4(precp_s[i], temp_s[i], lday_s[i], 0.0f);

    if (blockIdx.x == 0 && threadIdx.x < 64) {
        const int lane = threadIdx.x, hi = lane >> 4, m = lane & 15;
        half4v A1et, A1q, A2et, A2q, A3et, A3q;
        float4v C2et, C2q, C3et, C3q;
        #pragma unroll
        for (int j = 0; j < 4; j++) {
            int k = 4 * hi + j;
            float w1e = (k < 3) ? etW1[k * 16 + m] : ((k == 3) ? etb1[m] : 0.0f);
            float w1q = (k < 2) ? qW1 [k * 16 + m] : ((k == 2) ? qb1 [m] : 0.0f);
            A1et[j] = (_Float16)w1e;
            A1q [j] = (_Float16)w1q;
            A2et[j] = (_Float16)etW2[k * 16 + m];
            A2q [j] = (_Float16)qW2 [k * 16 + m];
            A3et[j] = (_Float16)etW3[k];     // replicated over all rows m
            A3q [j] = (_Float16)qW3 [k];
            C2et[j] = etb2[4 * hi + j];
            C2q [j] = qb2 [4 * hi + j];
            C3et[j] = etb3[0];
            C3q [j] = qb3 [0];
        }
        char* p = tbl + lane * 128;
        *(uint2*)(p +  0) = __builtin_bit_cast(uint2, A1et);
        *(uint2*)(p +  8) = __builtin_bit_cast(uint2, A1q);
        *(uint2*)(p + 16) = __builtin_bit_cast(uint2, A2et);
        *(uint2*)(p + 24) = __builtin_bit_cast(uint2, A2q);
        *(uint2*)(p + 32) = __builtin_bit_cast(uint2, A3et);
        *(uint2*)(p + 40) = __builtin_bit_cast(uint2, A3q);
        *(float4v*)(p + 48) = C2et;
        *(float4v*)(p + 64) = C2q;
        *(float4v*)(p + 80) = C3et;
        *(float4v*)(p + 96) = C3q;
    }
}

#define MFMA16(A, B, C) __builtin_amdgcn_mfma_f32_16x16x16f16((A), (B), (C), 0, 0, 0)

// MFMA 16x16x16 f16, swapped orientation: D = W^T . X  (cols = points).
// Shuffle-free layer chaining; layer-3 weights replicated -> cndmask pickup.
// PPT=2 stage-major; all state in NAMED scalars (arrays -> LDS, see r6).
// Fragments come from the precomputed table (7 vector loads).
__global__ __launch_bounds__(BLOCK) void exphydro_mfma_kernel(
    const float* __restrict__ t, const float* __restrict__ S_snow,
    const float* __restrict__ S_water,
    const float4* __restrict__ F, const char* __restrict__ tbl,
    const float* __restrict__ pDf, const float* __restrict__ pTmax,
    const float* __restrict__ pTmin,
    float* __restrict__ out, int N, int T)
{
    const int lane = threadIdx.x & 63;
    const int m    = lane & 15;
    const int wave = threadIdx.x >> 6;
    const int base = blockIdx.x * (BLOCK * PPT) + wave * (64 * PPT);

    // ---------- fragment loads from table ----------
    const char* tp_ = tbl + lane * 128;
    const half4v A1et = *(const half4v*)(tp_ +  0);
    const half4v A1q  = *(const half4v*)(tp_ +  8);
    const half4v A2et = *(const half4v*)(tp_ + 16);
    const half4v A2q  = *(const half4v*)(tp_ + 24);
    const half4v A3et = *(const half4v*)(tp_ + 32);
    const half4v A3q  = *(const half4v*)(tp_ + 40);
    const float4v C2et = *(const float4v*)(tp_ + 48);
    const float4v C2q  = *(const float4v*)(tp_ + 64);
    const float4v C3et = *(const float4v*)(tp_ + 80);
    const float4v C3q  = *(const float4v*)(tp_ + 96);

    const float Df   = pDf[0];
    const float Tmax = pTmax[0];
    const float Tmin = pTmin[0];
    const float tmaxf = (float)(T - 1);
    const int   imax  = T - 2;

    // bpermute byte-addresses for the 4 groups (computed once)
    const int ba0 = (( 0 + m) << 2);
    const int ba1 = ((16 + m) << 2);
    const int ba2 = ((32 + m) << 2);
    const int ba3 = ((48 + m) << 2);

    // ---------- per-point loads + interp, NAMED scalars ----------
    // i01 = (ss lo, sw hi); i23 = (pr lo, tp hi)  [pr in LO for alignbit]
#define LOAD_POINT(U, Pv, SSv, SWv, TPv, PRv, LDv, I01v, I23v)                 \
    const int Pv = base + (U) * 64 + lane;                                     \
    float SSv, SWv, TPv, PRv, LDv; unsigned I01v, I23v;                        \
    {                                                                          \
        int pc = (Pv < N) ? Pv : (N - 1);                                      \
        float tv = t[pc];                                                      \
        SSv = S_snow[pc];                                                      \
        SWv = S_water[pc];                                                     \
        float tc = fminf(fmaxf(tv, 0.0f), tmaxf);                              \
        int i0 = (int)tc;                                                      \
        i0 = (i0 > imax) ? imax : i0;                                          \
        float fr = tc - (float)i0;                                             \
        float4 f0 = F[i0];                                                     \
        float4 f1 = F[i0 + 1];                                                 \
        PRv = fmaf(fr, f1.x - f0.x, f0.x);                                     \
        TPv = fmaf(fr, f1.y - f0.y, f0.y);                                     \
        LDv = fmaf(fr, f1.z - f0.z, f0.z);                                     \
        I01v = __builtin_bit_cast(unsigned, cvt_pk_h2(SSv, SWv));              \
        I23v = __builtin_bit_cast(unsigned, cvt_pk_h2(PRv, TPv));              \
    }

    LOAD_POINT(0, p0, ss0, sw0, tp0, pr0, ld0, i01_0, i23_0)
    LOAD_POINT(1, p1, ss1, sw1, tp1, pr1, ld1, i01_1, i23_1)

    const float4v zero4 = {0.0f, 0.0f, 0.0f, 0.0f};

    // ---------- stage-major MLP for one point-set (4 groups breadth-first) ----
    // B1et = {ss,sw,tp,1}: w0 = j01, w1 = (j23>>16) | 1.0h<<16
    // B1q  = {sw,pr,1,0}:  w0 = (j23<<16)|(j01>>16) [alignbit], w1 = 1.0h
#define MLP_SET(I01v, I23v, E0, E1, E2, E3, Q0, Q1, Q2, Q3)                    \
    float E0, E1, E2, E3, Q0, Q1, Q2, Q3;                                      \
    {                                                                          \
        /* stage: bpermutes (8 independent) */                                 \
        unsigned j01_0 = (unsigned)__builtin_amdgcn_ds_bpermute(ba0, (int)I01v); \
        unsigned j23_0 = (unsigned)__builtin_amdgcn_ds_bpermute(ba0, (int)I23v); \
        unsigned j01_1 = (unsigned)__builtin_amdgcn_ds_bpermute(ba1, (int)I01v); \
        unsigned j23_1 = (unsigned)__builtin_amdgcn_ds_bpermute(ba1, (int)I23v); \
        unsigned j01_2 = (unsigned)__builtin_amdgcn_ds_bpermute(ba2, (int)I01v); \
        unsigned j23_2 = (unsigned)__builtin_amdgcn_ds_bpermute(ba2, (int)I23v); \
        unsigned j01_3 = (unsigned)__builtin_amdgcn_ds_bpermute(ba3, (int)I01v); \
        unsigned j23_3 = (unsigned)__builtin_amdgcn_ds_bpermute(ba3, (int)I23v); \
        /* stage: L1 MFMAs (8 independent) */                                  \
        float4v d1e0 = MFMA16(A1et, mk_h4(j01_0, 0x3C000000u | (j23_0 >> 16)), zero4); \
        float4v d1q0 = MFMA16(A1q,  mk_h4(align16(j23_0, j01_0), 0x3C00u), zero4); \
        float4v d1e1 = MFMA16(A1et, mk_h4(j01_1, 0x3C000000u | (j23_1 >> 16)), zero4); \
        float4v d1q1 = MFMA16(A1q,  mk_h4(align16(j23_1, j01_1), 0x3C00u), zero4); \
        float4v d1e2 = MFMA16(A1et, mk_h4(j01_2, 0x3C000000u | (j23_2 >> 16)), zero4); \
        float4v d1q2 = MFMA16(A1q,  mk_h4(align16(j23_2, j01_2), 0x3C00u), zero4); \
        float4v d1e3 = MFMA16(A1et, mk_h4(j01_3, 0x3C000000u | (j23_3 >> 16)), zero4); \
        float4v d1q3 = MFMA16(A1q,  mk_h4(align16(j23_3, j01_3), 0x3C00u), zero4); \
        /* stage: activations (8 independent) */                               \
        half4v b2e0 = act4(d1e0);  half4v b2q0 = act4(d1q0);                   \
        half4v b2e1 = act4(d1e1);  half4v b2q1 = act4(d1q1);                   \
        half4v b2e2 = act4(d1e2);  half4v b2q2 = act4(d1q2);                   \
        half4v b2e3 = act4(d1e3);  half4v b2q3 = act4(d1q3);                   \
        /* stage: L2 MFMAs */                                                  \
        float4v d2e0 = MFMA16(A2et, b2e0, C2et);  float4v d2q0 = MFMA16(A2q, b2q0, C2q); \
        float4v d2e1 = MFMA16(A2et, b2e1, C2et);  float4v d2q1 = MFMA16(A2q, b2q1, C2q); \
        float4v d2e2 = MFMA16(A2et, b2e2, C2et);  float4v d2q2 = MFMA16(A2q, b2q2, C2q); \
        float4v d2e3 = MFMA16(A2et, b2e3, C2et);  float4v d2q3 = MFMA16(A2q, b2q3, C2q); \
        /* stage: activations */                                               \
        half4v b3e0 = act4(d2e0);  half4v b3q0 = act4(d2q0);                   \
        half4v b3e1 = act4(d2e1);  half4v b3q1 = act4(d2q1);                   \
        half4v b3e2 = act4(d2e2);  half4v b3q2 = act4(d2q2);                   \
        half4v b3e3 = act4(d2e3);  half4v b3q3 = act4(d2q3);                   \
        /* stage: L3 MFMAs */                                                  \
        float4v d3e0 = MFMA16(A3et, b3e0, C3et);  float4v d3q0 = MFMA16(A3q, b3q0, C3q); \
        float4v d3e1 = MFMA16(A3et, b3e1, C3et);  float4v d3q1 = MFMA16(A3q, b3q1, C3q); \
        float4v d3e2 = MFMA16(A3et, b3e2, C3et);  float4v d3q2 = MFMA16(A3q, b3q2, C3q); \
        float4v d3e3 = MFMA16(A3et, b3e3, C3et);  float4v d3q3 = MFMA16(A3q, b3q3, C3q); \
        E0 = d3e0[0]; E1 = d3e1[0]; E2 = d3e2[0]; E3 = d3e3[0];                \
        Q0 = d3q0[0]; Q1 = d3q1[0]; Q2 = d3q2[0]; Q3 = d3q3[0];                \
    }

    MLP_SET(i01_0, i23_0, et00, et01, et02, et03, q00, q01, q02, q03)
    MLP_SET(i01_1, i23_1, et10, et11, et12, et13, q10, q11, q12, q13)

    // ---------- pickup + physics + store ----------
#define FINISH_POINT(Pv, SSv, SWv, TPv, PRv, LDv, E0, E1, E2, E3, Q0, Q1, Q2, Q3) \
    {                                                                          \
        float e01s = (lane & 16) ? E1 : E0;                                    \
        float e23s = (lane & 16) ? E3 : E2;                                    \
        float ET   = (lane & 32) ? e23s : e01s;                                \
        float q01s = (lane & 16) ? Q1 : Q0;                                    \
        float q23s = (lane & 16) ? Q3 : Q2;                                    \
        float Q    = (lane & 32) ? q23s : q01s;                                \
        float dT = TPv - Tmax;                                                 \
        half4v sargs = pk4_from_f32(5.0f * dT, 5.0f * SSv,                     \
                                    5.0f * (Tmin - TPv), 5.0f * SWv);          \
        half4v th = tanh_pk4(sargs);                                           \
        float stepA  = fmaf(0.5f, (float)th[0], 0.5f);                         \
        float stepSn = fmaf(0.5f, (float)th[1], 0.5f);                         \
        float stepPs = fmaf(0.5f, (float)th[2], 0.5f);                         \
        float sw01   = fmaf(0.5f, (float)th[3], 0.5f);                         \
        float melt = stepA * stepSn * fminf(SSv, Df * dT);                     \
        float Ps   = stepPs * PRv;                                             \
        float Pr   = (1.0f - stepPs) * PRv;                                    \
        float dS1 = Ps - melt;                                                 \
        float dS2 = Pr + melt - sw01 * (LDv * __expf(ET) + __expf(Q));         \
        if (Pv < N) {                                                          \
            out[Pv]     = dS1;                                                 \
            out[N + Pv] = dS2;                                                 \
        }                                                                      \
    }

    FINISH_POINT(p0, ss0, sw0, tp0, pr0, ld0, et00, et01, et02, et03, q00, q01, q02, q03)
    FINISH_POINT(p1, ss1, sw1, tp1, pr1, ld1, et10, et11, et12, et13, q10, q11, q12, q13)
}

extern "C" void kernel_launch(void* const* d_in, const int* in_sizes, int n_in,
                              void* d_out, int out_size, void* d_ws, size_t ws_size,
                              hipStream_t stream) {
    const float* t        = (const float*)d_in[0];
    const float* S_snow   = (const float*)d_in[1];
    const float* S_water  = (const float*)d_in[2];
    const float* precp_s  = (const float*)d_in[4];
    const float* temp_s   = (const float*)d_in[5];
    const float* lday_s   = (const float*)d_in[6];
    const float* etW1     = (const float*)d_in[7];
    const float* etb1     = (const float*)d_in[8];
    const float* etW2     = (const float*)d_in[9];
    const float* etb2     = (const float*)d_in[10];
    const float* etW3     = (const float*)d_in[11];
    const float* etb3     = (const float*)d_in[12];
    const float* qW1      = (const float*)d_in[13];
    const float* qb1      = (const float*)d_in[14];
    const float* qW2      = (const float*)d_in[15];
    const float* qb2      = (const float*)d_in[16];
    const float* qW3      = (const float*)d_in[17];
    const float* qb3      = (const float*)d_in[18];
    const float* pDf      = (const float*)d_in[19];
    const float* pTmax    = (const float*)d_in[20];
    const float* pTmin    = (const float*)d_in[21];

    int N = in_sizes[0];
    int T = in_sizes[3];
    float* out = (float*)d_out;
    float4* F = (float4*)d_ws;                              // T*16 bytes
    size_t tbl_off = (((size_t)T * 16) + 127) & ~(size_t)127;
    char* tbl = (char*)d_ws + tbl_off;                      // 64*128 = 8 KB

    prep_kernel<<<(T + BLOCK - 1) / BLOCK, BLOCK, 0, stream>>>(
        precp_s, temp_s, lday_s,
        etW1, etb1, etW2, etb2, etW3, etb3,
        qW1, qb1, qW2, qb2, qW3, qb3,
        F, tbl, T);

    int per_block = BLOCK * PPT;
    exphydro_mfma_kernel<<<(N + per_block - 1) / per_block, BLOCK, 0, stream>>>(
        t, S_snow, S_water, F, tbl,
        pDf, pTmax, pTmin, out, N, T);
}

// Round 11
// 41.799 us; speedup vs baseline: 1.0518x; 1.0518x over previous
//
#include <hip/hip_runtime.h>
#include <math.h>

#define BLOCK 256
#define PPT   2                 // points per thread (hand-unrolled, NO arrays)

typedef _Float16 half2v __attribute__((ext_vector_type(2)));
typedef _Float16 half4v __attribute__((ext_vector_type(4)));
typedef float    float4v __attribute__((ext_vector_type(4)));

__device__ __forceinline__ half2v cvt_pk_h2(float a, float b) {
    return __builtin_bit_cast(half2v, __builtin_amdgcn_cvt_pkrtz(a, b));
}

// build half4 from two packed-fp16 dwords (w0 -> elems 0,1; w1 -> elems 2,3)
__device__ __forceinline__ half4v mk_h4(unsigned w0, unsigned w1) {
    uint2 u; u.x = w0; u.y = w1;
    return __builtin_bit_cast(half4v, u);
}

#define H4(x) {(_Float16)(x), (_Float16)(x), (_Float16)(x), (_Float16)(x)}

// Packed-fp16 tanh: odd poly t*p(t^2), deg-5 in s, fit on s in [0,9], clamp
// |x|<=3, endpoint lifted so saturated units land on exactly +-1.0.
__device__ __forceinline__ half4v tanh_pk4(half4v x) {
    const half4v c5 = H4(-3.71625e-05f);
    const half4v c4 = H4( 1.09648e-03f);
    const half4v c3 = H4(-1.288264e-02f);
    const half4v c2 = H4( 7.941906e-02f);
    const half4v c1 = H4(-3.0042735e-01f);
    const half4v c0 = H4( 9.9607644e-01f);
    const half4v hi = H4( 3.0f);
    const half4v lo = H4(-3.0f);
    half4v t = __builtin_elementwise_min(__builtin_elementwise_max(x, lo), hi);
    half4v s = t * t;
#if __has_builtin(__builtin_elementwise_fma)
    half4v p = __builtin_elementwise_fma(c5, s, c4);
    p = __builtin_elementwise_fma(p, s, c3);
    p = __builtin_elementwise_fma(p, s, c2);
    p = __builtin_elementwise_fma(p, s, c1);
    p = __builtin_elementwise_fma(p, s, c0);
#else
    half4v p = c5 * s + c4;
    p = p * s + c3;
    p = p * s + c2;
    p = p * s + c1;
    p = p * s + c0;
#endif
    return t * p;
}

__device__ __forceinline__ half4v pk4_from_f32(float a, float b, float c, float d) {
    half2v lo = cvt_pk_h2(a, b);
    half2v hi = cvt_pk_h2(c, d);
    return __builtin_shufflevector(lo, hi, 0, 1, 2, 3);
}

__device__ __forceinline__ half4v act4(float4v d) {
    return tanh_pk4(pk4_from_f32(d[0], d[1], d[2], d[3]));
}

// ---- DS-free cross-lane: v_permlane{16,32}_swap (pure VALU) ----
// With vdst=vsrc=x the swap's two outputs hold {identity, cross} per row in
// HW-defined order; r[0]^r[1]^x extracts the cross value either way.
// Fallback uses lane (NOT threadIdx.x -- macro-param capture, see r10 fail).
#if __has_builtin(__builtin_amdgcn_permlane16_swap) && __has_builtin(__builtin_amdgcn_permlane32_swap)
#define SWAP16X(XV_) ({ auto _r = __builtin_amdgcn_permlane16_swap((XV_), (XV_), false, false); \
                        (unsigned)(_r[0] ^ _r[1] ^ (XV_)); })
#define SWAP32X(XV_) ({ auto _r = __builtin_amdgcn_permlane32_swap((XV_), (XV_), false, false); \
                        (unsigned)(_r[0] ^ _r[1] ^ (XV_)); })
#else
#define SWAP16X(XV_) ((unsigned)__shfl((int)(XV_), lane ^ 16, 64))
#define SWAP32X(XV_) ((unsigned)__shfl((int)(XV_), lane ^ 32, 64))
#endif

// Pack the 3 forcing series into an interleaved float4 table in d_ws.
__global__ __launch_bounds__(BLOCK) void pack_forcings_kernel(
    const float* __restrict__ precp_s, const float* __restrict__ temp_s,
    const float* __restrict__ lday_s, float4* __restrict__ F, int T)
{
    int i = blockIdx.x * BLOCK + threadIdx.x;
    if (i < T) F[i] = make_float4(precp_s[i], temp_s[i], lday_s[i], 0.0f);
}

#define MFMA16(A, B, C) __builtin_amdgcn_mfma_f32_16x16x16f16((A), (B), (C), 0, 0, 0)

// MFMA 16x16x16 f16, swapped orientation: D = W^T . X  (cols = points).
// Shuffle-free layer chaining; layer-3 weights replicated -> cndmask pickup.
// PPT=2 stage-major, NAMED scalars only (r6: arrays -> LDS disaster).
// ZERO DS-pipe ops: group redistribution via permlane swaps (VALU). Theory:
// r2 (DS-free) hit 92% VALUBusy; every bpermute round sits at 50-60% at any
// occupancy -> DS-queue convoy is the stall.
__global__ __launch_bounds__(BLOCK, 4) void exphydro_mfma_kernel(
    const float* __restrict__ t, const float* __restrict__ S_snow,
    const float* __restrict__ S_water,
    const float4* __restrict__ F,
    const float* __restrict__ etW1, const float* __restrict__ etb1,
    const float* __restrict__ etW2, const float* __restrict__ etb2,
    const float* __restrict__ etW3, const float* __restrict__ etb3,
    const float* __restrict__ qW1, const float* __restrict__ qb1,
    const float* __restrict__ qW2, const float* __restrict__ qb2,
    const float* __restrict__ qW3, const float* __restrict__ qb3,
    const float* __restrict__ pDf, const float* __restrict__ pTmax,
    const float* __restrict__ pTmin,
    float* __restrict__ out, int N, int T)
{
    const int lane = threadIdx.x & 63;
    const int hi   = lane >> 4;
    const int m    = lane & 15;
    const int wave = threadIdx.x >> 6;
    const int base = blockIdx.x * (BLOCK * PPT) + wave * (64 * PPT);

    // ---------- A-fragments (weights, transposed), fp16 ----------
    half4v A1et, A1q, A2et, A2q, A3et, A3q;
    float4v C2et, C2q, C3et, C3q;
    #pragma unroll
    for (int j = 0; j < 4; j++) {
        int k = 4 * hi + j;
        float w1e = (k < 3) ? etW1[k * 16 + m] : ((k == 3) ? etb1[m] : 0.0f);
        float w1q = (k < 2) ? qW1 [k * 16 + m] : ((k == 2) ? qb1 [m] : 0.0f);
        A1et[j] = (_Float16)w1e;
        A1q [j] = (_Float16)w1q;
        A2et[j] = (_Float16)etW2[k * 16 + m];
        A2q [j] = (_Float16)qW2 [k * 16 + m];
        A3et[j] = (_Float16)etW3[k];     // replicated over all rows m
        A3q [j] = (_Float16)qW3 [k];
        C2et[j] = etb2[4 * hi + j];
        C2q [j] = qb2 [4 * hi + j];
        C3et[j] = etb3[0];
        C3q [j] = qb3 [0];
    }

    const float Df   = pDf[0];
    const float Tmax = pTmax[0];
    const float Tmin = pTmin[0];
    const float tmaxf = (float)(T - 1);
    const int   imax  = T - 2;

    // ---------- per-point loads + interp, NAMED scalars ----------
    // i01 = (ss lo, sw hi); i23 = (tp lo, pr hi)
#define LOAD_POINT(U, Pv, SSv, SWv, TPv, PRv, LDv, I01v, I23v)                 \
    const int Pv = base + (U) * 64 + lane;                                     \
    float SSv, SWv, TPv, PRv, LDv; unsigned I01v, I23v;                        \
    {                                                                          \
        int pc = (Pv < N) ? Pv : (N - 1);                                      \
        float tv = t[pc];                                                      \
        SSv = S_snow[pc];                                                      \
        SWv = S_water[pc];                                                     \
        float tc = fminf(fmaxf(tv, 0.0f), tmaxf);                              \
        int i0 = (int)tc;                                                      \
        i0 = (i0 > imax) ? imax : i0;                                          \
        float fr = tc - (float)i0;                                             \
        float4 f0 = F[i0];                                                     \
        float4 f1 = F[i0 + 1];                                                 \
        PRv = fmaf(fr, f1.x - f0.x, f0.x);                                     \
        TPv = fmaf(fr, f1.y - f0.y, f0.y);                                     \
        LDv = fmaf(fr, f1.z - f0.z, f0.z);                                     \
        I01v = __builtin_bit_cast(unsigned, cvt_pk_h2(SSv, SWv));              \
        I23v = __builtin_bit_cast(unsigned, cvt_pk_h2(TPv, PRv));              \
    }

    LOAD_POINT(0, p0, ss0, sw0, tp0, pr0, ld0, i01_0, i23_0)
    LOAD_POINT(1, p1, ss1, sw1, tp1, pr1, ld1, i01_1, i23_1)

    const float4v zero4 = {0.0f, 0.0f, 0.0f, 0.0f};

    // ---------- stage-major MLP for one point-set (4 groups breadth-first) ----
    // B1et = {ss,sw,tp,1}: w0 = j01, w1 = 1.0h<<16 | (j23 & 0xFFFF)
    // B1q  = {sw,pr,1,0}:  w0 = (j01>>16) | (j23 & 0xFFFF0000), w1 = 1.0h
    // Only lanes 0-15 (hi==0) contribute nonzero B rows (A cols k>=4 are 0).
#define MLP_SET(I01v, I23v, E0, E1, E2, E3, Q0, Q1, Q2, Q3)                    \
    float E0, E1, E2, E3, Q0, Q1, Q2, Q3;                                      \
    {                                                                          \
        /* stage: cross-lane redistribution, pure VALU */                      \
        unsigned j01_0 = I01v;                                                 \
        unsigned j23_0 = I23v;                                                 \
        unsigned j01_1 = SWAP16X(I01v);                                        \
        unsigned j23_1 = SWAP16X(I23v);                                        \
        unsigned j01_2 = SWAP32X(I01v);                                        \
        unsigned j23_2 = SWAP32X(I23v);                                        \
        unsigned j01_3 = SWAP16X(j01_2);                                       \
        unsigned j23_3 = SWAP16X(j23_2);                                       \
        /* stage: L1 MFMAs (8 independent) */                                  \
        float4v d1e0 = MFMA16(A1et, mk_h4(j01_0, 0x3C000000u | (j23_0 & 0xFFFFu)), zero4); \
        float4v d1q0 = MFMA16(A1q,  mk_h4((j01_0 >> 16) | (j23_0 & 0xFFFF0000u), 0x3C00u), zero4); \
        float4v d1e1 = MFMA16(A1et, mk_h4(j01_1, 0x3C000000u | (j23_1 & 0xFFFFu)), zero4); \
        float4v d1q1 = MFMA16(A1q,  mk_h4((j01_1 >> 16) | (j23_1 & 0xFFFF0000u), 0x3C00u), zero4); \
        float4v d1e2 = MFMA16(A1et, mk_h4(j01_2, 0x3C000000u | (j23_2 & 0xFFFFu)), zero4); \
        float4v d1q2 = MFMA16(A1q,  mk_h4((j01_2 >> 16) | (j23_2 & 0xFFFF0000u), 0x3C00u), zero4); \
        float4v d1e3 = MFMA16(A1et, mk_h4(j01_3, 0x3C000000u | (j23_3 & 0xFFFFu)), zero4); \
        float4v d1q3 = MFMA16(A1q,  mk_h4((j01_3 >> 16) | (j23_3 & 0xFFFF0000u), 0x3C00u), zero4); \
        /* stage: activations (8 independent) */                               \
        half4v b2e0 = act4(d1e0);  half4v b2q0 = act4(d1q0);                   \
        half4v b2e1 = act4(d1e1);  half4v b2q1 = act4(d1q1);                   \
        half4v b2e2 = act4(d1e2);  half4v b2q2 = act4(d1q2);                   \
        half4v b2e3 = act4(d1e3);  half4v b2q3 = act4(d1q3);                   \
        /* stage: L2 MFMAs */                                                  \
        float4v d2e0 = MFMA16(A2et, b2e0, C2et);  float4v d2q0 = MFMA16(A2q, b2q0, C2q); \
        float4v d2e1 = MFMA16(A2et, b2e1, C2et);  float4v d2q1 = MFMA16(A2q, b2q1, C2q); \
        float4v d2e2 = MFMA16(A2et, b2e2, C2et);  float4v d2q2 = MFMA16(A2q, b2q2, C2q); \
        float4v d2e3 = MFMA16(A2et, b2e3, C2et);  float4v d2q3 = MFMA16(A2q, b2q3, C2q); \
        /* stage: activations */                                               \
        half4v b3e0 = act4(d2e0);  half4v b3q0 = act4(d2q0);                   \
        half4v b3e1 = act4(d2e1);  half4v b3q1 = act4(d2q1);                   \
        half4v b3e2 = act4(d2e2);  half4v b3q2 = act4(d2q2);                   \
        half4v b3e3 = act4(d2e3);  half4v b3q3 = act4(d2q3);                   \
        /* stage: L3 MFMAs */                                                  \
        float4v d3e0 = MFMA16(A3et, b3e0, C3et);  float4v d3q0 = MFMA16(A3q, b3q0, C3q); \
        float4v d3e1 = MFMA16(A3et, b3e1, C3et);  float4v d3q1 = MFMA16(A3q, b3q1, C3q); \
        float4v d3e2 = MFMA16(A3et, b3e2, C3et);  float4v d3q2 = MFMA16(A3q, b3q2, C3q); \
        float4v d3e3 = MFMA16(A3et, b3e3, C3et);  float4v d3q3 = MFMA16(A3q, b3q3, C3q); \
        E0 = d3e0[0]; E1 = d3e1[0]; E2 = d3e2[0]; E3 = d3e3[0];                \
        Q0 = d3q0[0]; Q1 = d3q1[0]; Q2 = d3q2[0]; Q3 = d3q3[0];                \
    }

    MLP_SET(i01_0, i23_0, et00, et01, et02, et03, q00, q01, q02, q03)
    MLP_SET(i01_1, i23_1, et10, et11, et12, et13, q10, q11, q12, q13)

    // ---------- pickup + physics + store ----------
#define FINISH_POINT(Pv, SSv, SWv, TPv, PRv, LDv, E0, E1, E2, E3, Q0, Q1, Q2, Q3) \
    {                                                                          \
        float e01s = (lane & 16) ? E1 : E0;                                    \
        float e23s = (lane & 16) ? E3 : E2;                                    \
        float ET   = (lane & 32) ? e23s : e01s;                                \
        float q01s = (lane & 16) ? Q1 : Q0;                                    \
        float q23s = (lane & 16) ? Q3 : Q2;                                    \
        float Q    = (lane & 32) ? q23s : q01s;                                \
        float dT = TPv - Tmax;                                                 \
        half4v sargs = pk4_from_f32(5.0f * dT, 5.0f * SSv,                     \
                                    5.0f * (Tmin - TPv), 5.0f * SWv);          \
        half4v th = tanh_pk4(sargs);                                           \
        float stepA  = fmaf(0.5f, (float)th[0], 0.5f);                         \
        float stepSn = fmaf(0.5f, (float)th[1], 0.5f);                         \
        float stepPs = fmaf(0.5f, (float)th[2], 0.5f);                         \
        float sw01   = fmaf(0.5f, (float)th[3], 0.5f);                         \
        float melt = stepA * stepSn * fminf(SSv, Df * dT);                     \
        float Ps   = stepPs * PRv;                                             \
        float Pr   = (1.0f - stepPs) * PRv;                                    \
        float dS1 = Ps - melt;                                                 \
        float dS2 = Pr + melt - sw01 * (LDv * __expf(ET) + __expf(Q));         \
        if (Pv < N) {                                                          \
            out[Pv]     = dS1;                                                 \
            out[N + Pv] = dS2;                                                 \
        }                                                                      \
    }

    FINISH_POINT(p0, ss0, sw0, tp0, pr0, ld0, et00, et01, et02, et03, q00, q01, q02, q03)
    FINISH_POINT(p1, ss1, sw1, tp1, pr1, ld1, et10, et11, et12, et13, q10, q11, q12, q13)
}

extern "C" void kernel_launch(void* const* d_in, const int* in_sizes, int n_in,
                              void* d_out, int out_size, void* d_ws, size_t ws_size,
                              hipStream_t stream) {
    const float* t        = (const float*)d_in[0];
    const float* S_snow   = (const float*)d_in[1];
    const float* S_water  = (const float*)d_in[2];
    const float* precp_s  = (const float*)d_in[4];
    const float* temp_s   = (const float*)d_in[5];
    const float* lday_s   = (const float*)d_in[6];
    const float* etW1     = (const float*)d_in[7];
    const float* etb1     = (const float*)d_in[8];
    const float* etW2     = (const float*)d_in[9];
    const float* etb2     = (const float*)d_in[10];
    const float* etW3     = (const float*)d_in[11];
    const float* etb3     = (const float*)d_in[12];
    const float* qW1      = (const float*)d_in[13];
    const float* qb1      = (const float*)d_in[14];
    const float* qW2      = (const float*)d_in[15];
    const float* qb2      = (const float*)d_in[16];
    const float* qW3      = (const float*)d_in[17];
    const float* qb3      = (const float*)d_in[18];
    const float* pDf      = (const float*)d_in[19];
    const float* pTmax    = (const float*)d_in[20];
    const float* pTmin    = (const float*)d_in[21];

    int N = in_sizes[0];
    int T = in_sizes[3];
    float* out = (float*)d_out;
    float4* F = (float4*)d_ws;   // T*16 bytes, fits ws

    pack_forcings_kernel<<<(T + BLOCK - 1) / BLOCK, BLOCK, 0, stream>>>(
        precp_s, temp_s, lday_s, F, T);

    int per_block = BLOCK * PPT;
    exphydro_mfma_kernel<<<(N + per_block - 1) / per_block, BLOCK, 0, stream>>>(
        t, S_snow, S_water, F,
        etW1, etb1, etW2, etb2, etW3, etb3,
        qW1, qb1, qW2, qb2, qW3, qb3,
        pDf, pTmax, pTmin, out, N, T);
}